// Round 6
// baseline (243.975 us; speedup 1.0000x reference)
//
#include <hip/hip_runtime.h>
#include <math.h>

// Problem constants (from reference setup_inputs)
#define BB 8
#define CC 19
#define HH 544
#define WW 960

// Tile: 64x64 outputs per 512-thread block. 960/64=15; H: 8 full + 1 partial(32).
#define TW 64
#define WT 72               // staged row stride: cols w0-4 .. w0+67 (f4-aligned)
#define BCP 68              // blurred row stride (TW+2 padded to 68)
#define HT_MAX 70           // 64+6 staged rows (full tile)
#define BR_MAX 66           // 64+2 blurred rows

#define SH_FLOATS   (HT_MAX * WT)       // 5040
#define STMP_FLOATS (BR_MAX * WT + 4)   // 4756 (+4: q=16 C-read spills 4 floats)
// sbl (66*68=4488 floats) aliases sh (dead after vertical pass)
// total LDS = 39184 B -> 4 blocks/CU x 8 waves = 32 waves/CU (hardware max)

// Grid: flattened 1D, 15*9*152 = 20520 blocks = 8 XCDs x 2565.
#define TILES_X 15
#define TILES_Y 9
#define NTILES_PLANE (TILES_X * TILES_Y)     // 135
#define NWG (TILES_X * TILES_Y * BB * CC)    // 20520
#define CHUNK (NWG / 8)                      // 2565 (exact)

typedef float f4 __attribute__((ext_vector_type(4)));

// bit-exactness vs numpy fp32 reference: never fuse mul+add, accumulate
// the 5-tap sum left-to-right (NMS blurred==maxes flips whole peaks on 1 ulp).
#pragma clang fp contract(off)

__device__ __forceinline__ int reflect_h(int i) {
    i = (i < 0) ? -i : i;
    return (i >= HH) ? (2 * HH - 2 - i) : i;
}
__device__ __forceinline__ int reflect_w(int i) {
    i = (i < 0) ? -i : i;
    return (i >= WW) ? (2 * WW - 2 - i) : i;
}

__device__ __forceinline__ float conv5(float s0, float s1, float s2, float s3,
                                       float s4, float k0, float k1, float k2,
                                       float k3, float k4) {
    #pragma clang fp contract(off)
    float v = s0 * k0;
    v = v + s1 * k1;
    v = v + s2 * k2;
    v = v + s3 * k3;
    v = v + s4 * k4;
    return v;
}

__global__ __launch_bounds__(512)
void skel_fused_kernel(const float* __restrict__ heat,
                       const float* __restrict__ k1d,
                       float* __restrict__ out)
{
    #pragma clang fp contract(off)

    __shared__ float smem[SH_FLOATS + STMP_FLOATS];
    float* const sh   = smem;                 // [ht_rows][WT]
    float* const stmp = smem + SH_FLOATS;     // [br_rows][WT]
    float* const sbl  = smem;                 // [br_rows][BCP], aliases sh

    // XCD-aware swizzle (T1, bijective since NWG % 8 == 0): dispatch assigns
    // XCD = wgid % 8; map so each XCD owns a contiguous run of spatially
    // adjacent tiles -> halo re-reads hit the same XCD's L2.
    const int wgid = blockIdx.x;
    const int s = (wgid & 7) * CHUNK + (wgid >> 3);
    const int pl = s / NTILES_PLANE;            // 0..151
    const int rem = s - pl * NTILES_PLANE;
    const int ht = rem / TILES_X;               // 0..8
    const int wt = rem - ht * TILES_X;          // 0..14

    const int h0 = ht * 64;
    const int w0 = wt * TW;
    const int tid = threadIdx.x;

    const int th_rows = (h0 + 64 <= HH) ? 64 : (HH - h0);  // 64, or 32 at ht=8
    const int ht_rows = th_rows + 6;
    const int br_rows = th_rows + 2;

    const float k0 = k1d[0], k1 = k1d[1], k2 = k1d[2], k3 = k1d[3], k4 = k1d[4];

    const float* __restrict__ plane = heat + (size_t)pl * (HH * WW);

    // interior <=> staged rows [h0-3, h0+67) and cols [w0-4, w0+68) in-image
    const bool interior = (wt >= 1) & (wt <= 13) & (ht >= 1) & (ht <= 7);

    // ---- stage heat tile: sh[r][c] = heat[h0-3+r][w0-4+c] ----
    if (interior) {
        for (int idx = tid; idx < ht_rows * (WT / 4); idx += 512) {
            const int r = idx / (WT / 4), q = idx % (WT / 4);
            const int gr = h0 - 3 + r;
            const int gc = w0 - 4 + q * 4;
            *(f4*)&sh[r * WT + q * 4] = *(const f4*)&plane[gr * WW + gc];
        }
    } else {
        for (int idx = tid; idx < ht_rows * WT; idx += 512) {
            const int r = idx / WT, c = idx % WT;
            const int gr = reflect_h(h0 - 3 + r);
            const int gc = reflect_w(w0 - 4 + c);
            sh[r * WT + c] = plane[gr * WW + gc];
        }
    }
    __syncthreads();

    // ---- vertical 5-tap pass: stmp[tr][*] from sh rows tr..tr+4 ----
    for (int idx = tid; idx < br_rows * (WT / 4); idx += 512) {
        const int tr = idx / (WT / 4), q = idx % (WT / 4);
        const f4 a0 = *(const f4*)&sh[(tr + 0) * WT + q * 4];
        const f4 a1 = *(const f4*)&sh[(tr + 1) * WT + q * 4];
        const f4 a2 = *(const f4*)&sh[(tr + 2) * WT + q * 4];
        const f4 a3 = *(const f4*)&sh[(tr + 3) * WT + q * 4];
        const f4 a4 = *(const f4*)&sh[(tr + 4) * WT + q * 4];
        f4 v;
        v.x = conv5(a0.x, a1.x, a2.x, a3.x, a4.x, k0, k1, k2, k3, k4);
        v.y = conv5(a0.y, a1.y, a2.y, a3.y, a4.y, k0, k1, k2, k3, k4);
        v.z = conv5(a0.z, a1.z, a2.z, a3.z, a4.z, k0, k1, k2, k3, k4);
        v.w = conv5(a0.w, a1.w, a2.w, a3.w, a4.w, k0, k1, k2, k3, k4);
        *(f4*)&stmp[tr * WT + q * 4] = v;
    }
    __syncthreads();

    // ---- horizontal 5-tap -> sbl (aliases sh; safe after the sync).
    // sbl col bc = blurred col (w0-1+bc); window = stmp scols bc+1 .. bc+5.
    // q=16: C spills into next stmp row / +4 pad; feeds only pad cols 66,67.
    for (int idx = tid; idx < br_rows * (BCP / 4); idx += 512) {
        const int br = idx / (BCP / 4), q = idx % (BCP / 4);
        const int bc0 = q * 4;
        const f4 A = *(const f4*)&stmp[br * WT + bc0];
        const f4 B = *(const f4*)&stmp[br * WT + bc0 + 4];
        const f4 C = *(const f4*)&stmp[br * WT + bc0 + 8];
        f4 v;
        v.x = conv5(A.y, A.z, A.w, B.x, B.y, k0, k1, k2, k3, k4);
        v.y = conv5(A.z, A.w, B.x, B.y, B.z, k0, k1, k2, k3, k4);
        v.z = conv5(A.w, B.x, B.y, B.z, B.w, k0, k1, k2, k3, k4);
        v.w = conv5(B.x, B.y, B.z, B.w, C.x, k0, k1, k2, k3, k4);
        if (!interior) {
            const int gbr = h0 - 1 + br;
            const bool rowok = (gbr >= 0) & (gbr < HH);
            const int gbc = w0 - 1 + bc0;
            v.x = (rowok & (gbc + 0 >= 0) & (gbc + 0 < WW)) ? v.x : -INFINITY;
            v.y = (rowok & (gbc + 1 >= 0) & (gbc + 1 < WW)) ? v.y : -INFINITY;
            v.z = (rowok & (gbc + 2 >= 0) & (gbc + 2 < WW)) ? v.z : -INFINITY;
            v.w = (rowok & (gbc + 3 >= 0) & (gbc + 3 < WW)) ? v.w : -INFINITY;
        }
        *(f4*)&sbl[br * BCP + bc0] = v;
    }
    __syncthreads();

    // ---- 3x3 max-pool + NMS + threshold; non-temporal f4 stores ----
    const size_t N = (size_t)BB * CC * HH * WW;
    float* __restrict__ out_peaks = out;
    float* __restrict__ out_maxes = out + N;
    float* __restrict__ out_blur  = out + 2 * N;

    for (int idx = tid; idx < th_rows * (TW / 4); idx += 512) {
        const int orow = idx >> 4, qc = idx & 15;
        const int oc0 = qc * 4;
        const f4 t0a = *(const f4*)&sbl[(orow + 0) * BCP + oc0];
        const f4 t0b = *(const f4*)&sbl[(orow + 0) * BCP + oc0 + 4];
        const f4 t1a = *(const f4*)&sbl[(orow + 1) * BCP + oc0];
        const f4 t1b = *(const f4*)&sbl[(orow + 1) * BCP + oc0 + 4];
        const f4 t2a = *(const f4*)&sbl[(orow + 2) * BCP + oc0];
        const f4 t2b = *(const f4*)&sbl[(orow + 2) * BCP + oc0 + 4];

        f4 r0, r1, r2;
        r0.x = fmaxf(fmaxf(t0a.x, t0a.y), t0a.z);
        r0.y = fmaxf(fmaxf(t0a.y, t0a.z), t0a.w);
        r0.z = fmaxf(fmaxf(t0a.z, t0a.w), t0b.x);
        r0.w = fmaxf(fmaxf(t0a.w, t0b.x), t0b.y);
        r1.x = fmaxf(fmaxf(t1a.x, t1a.y), t1a.z);
        r1.y = fmaxf(fmaxf(t1a.y, t1a.z), t1a.w);
        r1.z = fmaxf(fmaxf(t1a.z, t1a.w), t1b.x);
        r1.w = fmaxf(fmaxf(t1a.w, t1b.x), t1b.y);
        r2.x = fmaxf(fmaxf(t2a.x, t2a.y), t2a.z);
        r2.y = fmaxf(fmaxf(t2a.y, t2a.z), t2a.w);
        r2.z = fmaxf(fmaxf(t2a.z, t2a.w), t2b.x);
        r2.w = fmaxf(fmaxf(t2a.w, t2b.x), t2b.y);

        f4 m;
        m.x = fmaxf(fmaxf(r0.x, r1.x), r2.x);
        m.y = fmaxf(fmaxf(r0.y, r1.y), r2.y);
        m.z = fmaxf(fmaxf(r0.z, r1.z), r2.z);
        m.w = fmaxf(fmaxf(r0.w, r1.w), r2.w);

        f4 b;
        b.x = t1a.y; b.y = t1a.z; b.z = t1a.w; b.w = t1b.x;

        // numpy compares fp32 promoted to fp64 vs python 0.1: b==0.1f kept -> >=
        f4 p;
        p.x = (b.x == m.x && b.x >= 0.1f) ? b.x : 0.0f;
        p.y = (b.y == m.y && b.y >= 0.1f) ? b.y : 0.0f;
        p.z = (b.z == m.z && b.z >= 0.1f) ? b.z : 0.0f;
        p.w = (b.w == m.w && b.w >= 0.1f) ? b.w : 0.0f;

        const size_t o = (size_t)pl * (HH * WW) + (size_t)(h0 + orow) * WW + (w0 + oc0);
        __builtin_nontemporal_store(p, (f4*)&out_peaks[o]);
        __builtin_nontemporal_store(m, (f4*)&out_maxes[o]);
        __builtin_nontemporal_store(b, (f4*)&out_blur[o]);
    }
}

extern "C" void kernel_launch(void* const* d_in, const int* in_sizes, int n_in,
                              void* d_out, int out_size, void* d_ws, size_t ws_size,
                              hipStream_t stream) {
    const float* heat = (const float*)d_in[0];
    const float* k1d  = (const float*)d_in[1];
    float* out = (float*)d_out;

    dim3 grid(NWG);          // flattened; swizzled inside the kernel
    dim3 block(512);
    skel_fused_kernel<<<grid, block, 0, stream>>>(heat, k1d, out);
}

// Round 7
// 227.309 us; speedup vs baseline: 1.0733x; 1.0733x over previous
//
#include <hip/hip_runtime.h>
#include <math.h>

// Problem constants (from reference setup_inputs)
#define BB 8
#define CC 19
#define HH 544
#define WW 960

// Tile: 64x64 outputs per 512-thread block. 960/64=15; H: 8 full + 1 partial(32).
#define TW 64
#define WT 72               // staged row stride: cols w0-4 .. w0+67 (f4-aligned)
#define BCP 68              // blurred row stride (TW+2 padded to 68)
#define HT_MAX 70           // 64+6 staged rows (full tile)
#define BR_MAX 66           // 64+2 blurred rows

#define SH_FLOATS   (HT_MAX * WT)       // 5040
#define STMP_FLOATS (BR_MAX * WT + 4)   // 4756 (+4: q=16 C-read spills 4 floats)
// sbl (66*68=4488 floats) aliases sh (dead after vertical pass)
// total LDS = 39184 B -> 4 blocks/CU x 8 waves = 32 waves/CU (hardware max)
//
// NOTE (R6 post-mortem): XCD-aware swizzle of the flattened grid REGRESSED
// 227 -> 244 us. Default 3D dispatch already absorbs the 23% halo re-reads
// (temporal locality + L3); keep the plain grid.

typedef float f4 __attribute__((ext_vector_type(4)));

// bit-exactness vs numpy fp32 reference: never fuse mul+add, accumulate
// the 5-tap sum left-to-right (NMS blurred==maxes flips whole peaks on 1 ulp).
#pragma clang fp contract(off)

__device__ __forceinline__ int reflect_h(int i) {
    i = (i < 0) ? -i : i;
    return (i >= HH) ? (2 * HH - 2 - i) : i;
}
__device__ __forceinline__ int reflect_w(int i) {
    i = (i < 0) ? -i : i;
    return (i >= WW) ? (2 * WW - 2 - i) : i;
}

__device__ __forceinline__ float conv5(float s0, float s1, float s2, float s3,
                                       float s4, float k0, float k1, float k2,
                                       float k3, float k4) {
    #pragma clang fp contract(off)
    float v = s0 * k0;
    v = v + s1 * k1;
    v = v + s2 * k2;
    v = v + s3 * k3;
    v = v + s4 * k4;
    return v;
}

__global__ __launch_bounds__(512)
void skel_fused_kernel(const float* __restrict__ heat,
                       const float* __restrict__ k1d,
                       float* __restrict__ out)
{
    #pragma clang fp contract(off)

    __shared__ float smem[SH_FLOATS + STMP_FLOATS];
    float* const sh   = smem;                 // [ht_rows][WT]
    float* const stmp = smem + SH_FLOATS;     // [br_rows][WT]
    float* const sbl  = smem;                 // [br_rows][BCP], aliases sh

    const int wt = blockIdx.x;      // 0..14
    const int ht = blockIdx.y;      // 0..8
    const int pl = blockIdx.z;      // 0..151
    const int h0 = ht * 64;
    const int w0 = wt * TW;
    const int tid = threadIdx.x;

    const int th_rows = (h0 + 64 <= HH) ? 64 : (HH - h0);  // 64, or 32 at ht=8
    const int ht_rows = th_rows + 6;
    const int br_rows = th_rows + 2;

    const float k0 = k1d[0], k1 = k1d[1], k2 = k1d[2], k3 = k1d[3], k4 = k1d[4];

    const float* __restrict__ plane = heat + (size_t)pl * (HH * WW);

    // interior <=> staged rows [h0-3, h0+67) and cols [w0-4, w0+68) in-image
    const bool interior = (wt >= 1) & (wt <= 13) & (ht >= 1) & (ht <= 7);

    // ---- stage heat tile: sh[r][c] = heat[h0-3+r][w0-4+c] ----
    if (interior) {
        for (int idx = tid; idx < ht_rows * (WT / 4); idx += 512) {
            const int r = idx / (WT / 4), q = idx % (WT / 4);
            const int gr = h0 - 3 + r;
            const int gc = w0 - 4 + q * 4;
            *(f4*)&sh[r * WT + q * 4] = *(const f4*)&plane[gr * WW + gc];
        }
    } else {
        for (int idx = tid; idx < ht_rows * WT; idx += 512) {
            const int r = idx / WT, c = idx % WT;
            const int gr = reflect_h(h0 - 3 + r);
            const int gc = reflect_w(w0 - 4 + c);
            sh[r * WT + c] = plane[gr * WW + gc];
        }
    }
    __syncthreads();

    // ---- vertical 5-tap pass: stmp[tr][*] from sh rows tr..tr+4 ----
    for (int idx = tid; idx < br_rows * (WT / 4); idx += 512) {
        const int tr = idx / (WT / 4), q = idx % (WT / 4);
        const f4 a0 = *(const f4*)&sh[(tr + 0) * WT + q * 4];
        const f4 a1 = *(const f4*)&sh[(tr + 1) * WT + q * 4];
        const f4 a2 = *(const f4*)&sh[(tr + 2) * WT + q * 4];
        const f4 a3 = *(const f4*)&sh[(tr + 3) * WT + q * 4];
        const f4 a4 = *(const f4*)&sh[(tr + 4) * WT + q * 4];
        f4 v;
        v.x = conv5(a0.x, a1.x, a2.x, a3.x, a4.x, k0, k1, k2, k3, k4);
        v.y = conv5(a0.y, a1.y, a2.y, a3.y, a4.y, k0, k1, k2, k3, k4);
        v.z = conv5(a0.z, a1.z, a2.z, a3.z, a4.z, k0, k1, k2, k3, k4);
        v.w = conv5(a0.w, a1.w, a2.w, a3.w, a4.w, k0, k1, k2, k3, k4);
        *(f4*)&stmp[tr * WT + q * 4] = v;
    }
    __syncthreads();

    // ---- horizontal 5-tap -> sbl (aliases sh; safe after the sync).
    // sbl col bc = blurred col (w0-1+bc); window = stmp scols bc+1 .. bc+5.
    // q=16: C spills into next stmp row / +4 pad; feeds only pad cols 66,67.
    for (int idx = tid; idx < br_rows * (BCP / 4); idx += 512) {
        const int br = idx / (BCP / 4), q = idx % (BCP / 4);
        const int bc0 = q * 4;
        const f4 A = *(const f4*)&stmp[br * WT + bc0];
        const f4 B = *(const f4*)&stmp[br * WT + bc0 + 4];
        const f4 C = *(const f4*)&stmp[br * WT + bc0 + 8];
        f4 v;
        v.x = conv5(A.y, A.z, A.w, B.x, B.y, k0, k1, k2, k3, k4);
        v.y = conv5(A.z, A.w, B.x, B.y, B.z, k0, k1, k2, k3, k4);
        v.z = conv5(A.w, B.x, B.y, B.z, B.w, k0, k1, k2, k3, k4);
        v.w = conv5(B.x, B.y, B.z, B.w, C.x, k0, k1, k2, k3, k4);
        if (!interior) {
            const int gbr = h0 - 1 + br;
            const bool rowok = (gbr >= 0) & (gbr < HH);
            const int gbc = w0 - 1 + bc0;
            v.x = (rowok & (gbc + 0 >= 0) & (gbc + 0 < WW)) ? v.x : -INFINITY;
            v.y = (rowok & (gbc + 1 >= 0) & (gbc + 1 < WW)) ? v.y : -INFINITY;
            v.z = (rowok & (gbc + 2 >= 0) & (gbc + 2 < WW)) ? v.z : -INFINITY;
            v.w = (rowok & (gbc + 3 >= 0) & (gbc + 3 < WW)) ? v.w : -INFINITY;
        }
        *(f4*)&sbl[br * BCP + bc0] = v;
    }
    __syncthreads();

    // ---- 3x3 max-pool + NMS + threshold; non-temporal f4 stores ----
    const size_t N = (size_t)BB * CC * HH * WW;
    float* __restrict__ out_peaks = out;
    float* __restrict__ out_maxes = out + N;
    float* __restrict__ out_blur  = out + 2 * N;

    for (int idx = tid; idx < th_rows * (TW / 4); idx += 512) {
        const int orow = idx >> 4, qc = idx & 15;
        const int oc0 = qc * 4;
        const f4 t0a = *(const f4*)&sbl[(orow + 0) * BCP + oc0];
        const f4 t0b = *(const f4*)&sbl[(orow + 0) * BCP + oc0 + 4];
        const f4 t1a = *(const f4*)&sbl[(orow + 1) * BCP + oc0];
        const f4 t1b = *(const f4*)&sbl[(orow + 1) * BCP + oc0 + 4];
        const f4 t2a = *(const f4*)&sbl[(orow + 2) * BCP + oc0];
        const f4 t2b = *(const f4*)&sbl[(orow + 2) * BCP + oc0 + 4];

        f4 r0, r1, r2;
        r0.x = fmaxf(fmaxf(t0a.x, t0a.y), t0a.z);
        r0.y = fmaxf(fmaxf(t0a.y, t0a.z), t0a.w);
        r0.z = fmaxf(fmaxf(t0a.z, t0a.w), t0b.x);
        r0.w = fmaxf(fmaxf(t0a.w, t0b.x), t0b.y);
        r1.x = fmaxf(fmaxf(t1a.x, t1a.y), t1a.z);
        r1.y = fmaxf(fmaxf(t1a.y, t1a.z), t1a.w);
        r1.z = fmaxf(fmaxf(t1a.z, t1a.w), t1b.x);
        r1.w = fmaxf(fmaxf(t1a.w, t1b.x), t1b.y);
        r2.x = fmaxf(fmaxf(t2a.x, t2a.y), t2a.z);
        r2.y = fmaxf(fmaxf(t2a.y, t2a.z), t2a.w);
        r2.z = fmaxf(fmaxf(t2a.z, t2a.w), t2b.x);
        r2.w = fmaxf(fmaxf(t2a.w, t2b.x), t2b.y);

        f4 m;
        m.x = fmaxf(fmaxf(r0.x, r1.x), r2.x);
        m.y = fmaxf(fmaxf(r0.y, r1.y), r2.y);
        m.z = fmaxf(fmaxf(r0.z, r1.z), r2.z);
        m.w = fmaxf(fmaxf(r0.w, r1.w), r2.w);

        f4 b;
        b.x = t1a.y; b.y = t1a.z; b.z = t1a.w; b.w = t1b.x;

        // numpy compares fp32 promoted to fp64 vs python 0.1: b==0.1f kept -> >=
        f4 p;
        p.x = (b.x == m.x && b.x >= 0.1f) ? b.x : 0.0f;
        p.y = (b.y == m.y && b.y >= 0.1f) ? b.y : 0.0f;
        p.z = (b.z == m.z && b.z >= 0.1f) ? b.z : 0.0f;
        p.w = (b.w == m.w && b.w >= 0.1f) ? b.w : 0.0f;

        const size_t o = (size_t)pl * (HH * WW) + (size_t)(h0 + orow) * WW + (w0 + oc0);
        __builtin_nontemporal_store(p, (f4*)&out_peaks[o]);
        __builtin_nontemporal_store(m, (f4*)&out_maxes[o]);
        __builtin_nontemporal_store(b, (f4*)&out_blur[o]);
    }
}

extern "C" void kernel_launch(void* const* d_in, const int* in_sizes, int n_in,
                              void* d_out, int out_size, void* d_ws, size_t ws_size,
                              hipStream_t stream) {
    const float* heat = (const float*)d_in[0];
    const float* k1d  = (const float*)d_in[1];
    float* out = (float*)d_out;

    dim3 grid(WW / TW, (HH + 63) / 64, BB * CC);   // 15 x 9 x 152
    dim3 block(512);
    skel_fused_kernel<<<grid, block, 0, stream>>>(heat, k1d, out);
}